// Round 1
// baseline (594.320 us; speedup 1.0000x reference)
//
#include <hip/hip_runtime.h>
#include <math.h>

#define N_NODESC 100000
#define N_EDGESC 1600000
#define NBLK_SCAN 98   // ceil(100000/1024)

// ---------------- degree histogram ----------------
__global__ void deg_kernel(const int* __restrict__ src, const int* __restrict__ dst,
                           int* __restrict__ deg_out, int* __restrict__ deg_in) {
    int i = blockIdx.x * blockDim.x + threadIdx.x;
    int stride = gridDim.x * blockDim.x;
    for (; i < N_EDGESC; i += stride) {
        atomicAdd(&deg_out[src[i]], 1);
        atomicAdd(&deg_in[dst[i]], 1);
    }
}

// ---------------- fused fc1 (tanh) + filt GEMM, xs = x * inv_sqrt_out ----------------
// block = 256 threads, tile = 128 nodes. feat tile in LDS (stride 68 for aligned
// b128 reads); weights read with wave-uniform indices -> s_load into SGPRs.
__global__ __launch_bounds__(256) void gemm_kernel(
    const float* __restrict__ feat,
    const float* __restrict__ w1, const float* __restrict__ b1,
    const float* __restrict__ w2, const float* __restrict__ b2,
    const int* __restrict__ deg_out,
    float* __restrict__ h1, float* __restrict__ xs) {
    __shared__ float sf[128 * 68];
    int tid = threadIdx.x;
    int base = blockIdx.x * 128;
    // stage feat tile: 128*64 floats = 2048 float4, 8 per thread, coalesced
    for (int k = 0; k < 8; k++) {
        int fi = tid + k * 256;          // float4 index in tile
        int node = fi >> 4, f4 = fi & 15;
        float4 v = make_float4(0.f, 0.f, 0.f, 0.f);
        if (base + node < N_NODESC)
            v = ((const float4*)feat)[(size_t)(base + node) * 16 + f4];
        float* d = &sf[node * 68 + f4 * 4];
        d[0] = v.x; d[1] = v.y; d[2] = v.z; d[3] = v.w;
    }
    __syncthreads();

    int lane = tid & 63;
    int og = __builtin_amdgcn_readfirstlane(tid >> 6);   // wave-uniform output group
    const float* wp1 = w1 + og * 16 * 64;
    const float* wp2 = w2 + og * 16 * 64;

    float a1[2][16], a2[2][16];
#pragma unroll
    for (int o = 0; o < 16; o++) {
        float bb1 = b1[og * 16 + o], bb2 = b2[og * 16 + o];
        a1[0][o] = bb1; a1[1][o] = bb1;
        a2[0][o] = bb2; a2[1][o] = bb2;
    }

    for (int fq = 0; fq < 16; fq++) {
        float4 fv0 = *(const float4*)&sf[lane * 68 + fq * 4];
        float4 fv1 = *(const float4*)&sf[(lane + 64) * 68 + fq * 4];
#pragma unroll
        for (int o = 0; o < 16; o++) {
            float4 wv1 = *(const float4*)&wp1[o * 64 + fq * 4];   // uniform -> s_load
            float4 wv2 = *(const float4*)&wp2[o * 64 + fq * 4];
            a1[0][o] += fv0.x * wv1.x + fv0.y * wv1.y + fv0.z * wv1.z + fv0.w * wv1.w;
            a1[1][o] += fv1.x * wv1.x + fv1.y * wv1.y + fv1.z * wv1.z + fv1.w * wv1.w;
            a2[0][o] += fv0.x * wv2.x + fv0.y * wv2.y + fv0.z * wv2.z + fv0.w * wv2.w;
            a2[1][o] += fv1.x * wv2.x + fv1.y * wv2.y + fv1.z * wv2.z + fv1.w * wv2.w;
        }
    }

#pragma unroll
    for (int j = 0; j < 2; j++) {
        int g = base + lane + j * 64;
        if (g >= N_NODESC) continue;
        float is = rsqrtf(fmaxf((float)deg_out[g], 1.f));
#pragma unroll
        for (int oq = 0; oq < 4; oq++) {
            float4 t, u;
            t.x = tanhf(a1[j][oq * 4 + 0]); t.y = tanhf(a1[j][oq * 4 + 1]);
            t.z = tanhf(a1[j][oq * 4 + 2]); t.w = tanhf(a1[j][oq * 4 + 3]);
            u.x = a2[j][oq * 4 + 0] * is;   u.y = a2[j][oq * 4 + 1] * is;
            u.z = a2[j][oq * 4 + 2] * is;   u.w = a2[j][oq * 4 + 3] * is;
            ((float4*)h1)[(size_t)g * 16 + og * 4 + oq] = t;
            ((float4*)xs)[(size_t)g * 16 + og * 4 + oq] = u;
        }
    }
}

// ---------------- 3-phase exclusive scan of deg_in ----------------
__global__ __launch_bounds__(1024) void scanA_kernel(const int* __restrict__ deg,
                                                     int* __restrict__ part,
                                                     int* __restrict__ blk_sums) {
    int i = blockIdx.x * 1024 + threadIdx.x;
    int lane = threadIdx.x & 63, wid = threadIdx.x >> 6;
    int orig = (i < N_NODESC) ? deg[i] : 0;
    int v = orig;
#pragma unroll
    for (int off = 1; off < 64; off <<= 1) {
        int t = __shfl_up(v, off, 64);
        if (lane >= off) v += t;
    }
    __shared__ int wsums[16];
    if (lane == 63) wsums[wid] = v;
    __syncthreads();
    if (wid == 0) {
        int s = (lane < 16) ? wsums[lane] : 0;
#pragma unroll
        for (int off = 1; off < 16; off <<= 1) {
            int t = __shfl_up(s, off, 64);
            if (lane >= off) s += t;
        }
        if (lane < 16) wsums[lane] = s;
    }
    __syncthreads();
    int woff = (wid > 0) ? wsums[wid - 1] : 0;
    int incl = v + woff;
    if (i < N_NODESC) part[i] = incl - orig;
    if (threadIdx.x == 1023) blk_sums[blockIdx.x] = incl;
}

__global__ void scanB_kernel(const int* __restrict__ bs, int* __restrict__ bo) {
    int lane = threadIdx.x;  // 64 threads
    int v0 = (lane < NBLK_SCAN) ? bs[lane] : 0;
    int v1 = (lane + 64 < NBLK_SCAN) ? bs[lane + 64] : 0;
    int o0 = v0, o1 = v1;
#pragma unroll
    for (int off = 1; off < 64; off <<= 1) {
        int t = __shfl_up(v0, off, 64);
        if (lane >= off) v0 += t;
    }
    int tot0 = __shfl(v0, 63, 64);
#pragma unroll
    for (int off = 1; off < 64; off <<= 1) {
        int t = __shfl_up(v1, off, 64);
        if (lane >= off) v1 += t;
    }
    v1 += tot0;
    if (lane < NBLK_SCAN) bo[lane] = v0 - o0;
    if (lane + 64 < NBLK_SCAN) bo[lane + 64] = v1 - o1;
}

__global__ void scanC_kernel(const int* __restrict__ part, const int* __restrict__ bo,
                             int* __restrict__ row_start, int* __restrict__ cursor) {
    int i = blockIdx.x * 256 + threadIdx.x;
    if (i < N_NODESC) {
        int v = part[i] + bo[i >> 10];
        row_start[i] = v;
        cursor[i] = v;
    }
    if (i == N_NODESC) row_start[N_NODESC] = N_EDGESC;
}

// ---------------- counting-sort fill: group edges by dst, keep src ----------------
__global__ void fill_kernel(const int* __restrict__ src, const int* __restrict__ dst,
                            int* __restrict__ cursor, int* __restrict__ srcs) {
    int i = blockIdx.x * blockDim.x + threadIdx.x;
    int stride = gridDim.x * blockDim.x;
    for (; i < N_EDGESC; i += stride) {
        int d = dst[i];
        int slot = atomicAdd(&cursor[d], 1);
        srcs[slot] = src[i];
    }
}

// ---------------- aggregation: one wave per dst node, lane = feature ----------------
__global__ __launch_bounds__(256) void agg_kernel(const int* __restrict__ row_start,
                                                  const int* __restrict__ srcs,
                                                  const float* __restrict__ xs,
                                                  float* __restrict__ h2) {
    int node = blockIdx.x * 4 + (threadIdx.x >> 6);
    int lane = threadIdx.x & 63;
    if (node >= N_NODESC) return;
    int beg = row_start[node], end = row_start[node + 1];
    float acc = 0.f;
    for (int s = beg; s < end; s += 64) {
        int idx = s + lane;
        int sv = (idx < end) ? srcs[idx] : 0;
        int cnt = min(64, end - s);
        for (int j = 0; j < cnt; j++) {
            int sj = __shfl(sv, j, 64);
            acc += xs[(size_t)sj * 64 + lane];
        }
    }
    float isq = rsqrtf(fmaxf((float)(end - beg), 1.f));
    h2[(size_t)node * 64 + lane] = acc * isq;
}

// ---------------- channel-attention scores (sum over nodes) ----------------
__global__ __launch_bounds__(256) void att_kernel(const float* __restrict__ h1,
                                                  const float* __restrict__ h2,
                                                  const float* __restrict__ aw1,
                                                  const float* __restrict__ ab1,
                                                  const float* __restrict__ aw2,
                                                  float* __restrict__ wsum) {
    int n = blockIdx.x * 256 + threadIdx.x;
    float sc[2] = {0.f, 0.f};
    if (n < N_NODESC) {
#pragma unroll
        for (int c = 0; c < 2; c++) {
            const float* row = (c == 0 ? h1 : h2) + (size_t)n * 64;
            float acc[32];
#pragma unroll
            for (int k = 0; k < 32; k++) acc[k] = ab1[k];
            for (int fq = 0; fq < 16; fq++) {
                float4 rv = ((const float4*)row)[fq];
#pragma unroll
                for (int k = 0; k < 32; k++) {
                    acc[k] += rv.x * aw1[(fq * 4 + 0) * 32 + k]
                            + rv.y * aw1[(fq * 4 + 1) * 32 + k]
                            + rv.z * aw1[(fq * 4 + 2) * 32 + k]
                            + rv.w * aw1[(fq * 4 + 3) * 32 + k];
                }
            }
            float s = 0.f;
#pragma unroll
            for (int k = 0; k < 32; k++) s += tanhf(acc[k]) * aw2[k];
            sc[c] = s;
        }
    }
#pragma unroll
    for (int off = 32; off; off >>= 1) {
        sc[0] += __shfl_down(sc[0], off, 64);
        sc[1] += __shfl_down(sc[1], off, 64);
    }
    if ((threadIdx.x & 63) == 0) {
        atomicAdd(&wsum[0], sc[0]);
        atomicAdd(&wsum[1], sc[1]);
    }
}

__global__ void beta_kernel(const float* __restrict__ wsum, float* __restrict__ beta) {
    float w0 = wsum[0] / (float)N_NODESC, w1 = wsum[1] / (float)N_NODESC;
    float m = fmaxf(w0, w1);
    float e0 = expf(w0 - m), e1 = expf(w1 - m);
    float inv = 1.f / (e0 + e1);
    beta[0] = e0 * inv;
    beta[1] = e1 * inv;
}

// ---------------- fused combine + fc2 ----------------
__global__ __launch_bounds__(256) void out_kernel(const float* __restrict__ h1,
                                                  const float* __restrict__ h2,
                                                  const float* __restrict__ beta,
                                                  const float* __restrict__ w,
                                                  const float* __restrict__ b,
                                                  float* __restrict__ out) {
    __shared__ float sw[16 * 68];
    int tid = threadIdx.x;
    {   // 16x64 weights = 256 float4
        int o = tid >> 4, f4 = tid & 15;
        float4 v = ((const float4*)w)[tid];
        float* d = &sw[o * 68 + f4 * 4];
        d[0] = v.x; d[1] = v.y; d[2] = v.z; d[3] = v.w;
    }
    __syncthreads();
    int o = tid & 15, ln = tid >> 4;
    int node = blockIdx.x * 16 + ln;
    if (node >= N_NODESC) return;
    float b0 = beta[0], b1v = beta[1];
    const float4* r1 = (const float4*)(h1 + (size_t)node * 64);
    const float4* r2 = (const float4*)(h2 + (size_t)node * 64);
    float acc = b[o];
    for (int fq = 0; fq < 16; fq++) {
        float4 x1 = r1[fq], x2 = r2[fq];
        float4 wv = *(const float4*)&sw[o * 68 + fq * 4];
        acc += (b0 * x1.x + b1v * x2.x) * wv.x + (b0 * x1.y + b1v * x2.y) * wv.y
             + (b0 * x1.z + b1v * x2.z) * wv.z + (b0 * x1.w + b1v * x2.w) * wv.w;
    }
    out[(size_t)node * 16 + o] = acc;
}

extern "C" void kernel_launch(void* const* d_in, const int* in_sizes, int n_in,
                              void* d_out, int out_size, void* d_ws, size_t ws_size,
                              hipStream_t stream) {
    (void)in_sizes; (void)n_in; (void)out_size; (void)ws_size;
    const float* feat = (const float*)d_in[0];
    const int*   esrc = (const int*)d_in[1];
    const int*   edst = (const int*)d_in[2];
    const float* fc1w = (const float*)d_in[3];
    const float* fc1b = (const float*)d_in[4];
    const float* fltw = (const float*)d_in[5];
    const float* fltb = (const float*)d_in[6];
    const float* aw1  = (const float*)d_in[7];
    const float* ab1  = (const float*)d_in[8];
    const float* aw2  = (const float*)d_in[9];
    const float* fc2w = (const float*)d_in[10];
    const float* fc2b = (const float*)d_in[11];
    float* out = (float*)d_out;

    char* ws = (char*)d_ws;
    size_t off = 0;
    auto alloc = [&](size_t bytes) {
        char* p = ws + off;
        off += (bytes + 255) & ~(size_t)255;
        return p;
    };
    float* h1        = (float*)alloc((size_t)N_NODESC * 64 * 4);
    float* xs        = (float*)alloc((size_t)N_NODESC * 64 * 4);
    float* h2        = (float*)alloc((size_t)N_NODESC * 64 * 4);
    int*   deg_out   = (int*)alloc((size_t)N_NODESC * 4);
    int*   deg_in    = (int*)alloc((size_t)N_NODESC * 4);
    int*   row_start = (int*)alloc((size_t)(N_NODESC + 1) * 4);
    int*   cursor    = (int*)alloc((size_t)N_NODESC * 4);
    int*   srcs      = (int*)alloc((size_t)N_EDGESC * 4);
    int*   blk_sums  = (int*)alloc(256 * 4);
    int*   blk_off   = (int*)alloc(256 * 4);
    float* wsum      = (float*)alloc(16 * 4);
    float* beta      = (float*)alloc(16 * 4);

    hipMemsetAsync(deg_out, 0, (size_t)N_NODESC * 4, stream);
    hipMemsetAsync(deg_in, 0, (size_t)N_NODESC * 4, stream);
    hipMemsetAsync(wsum, 0, 2 * 4, stream);

    deg_kernel<<<1024, 256, 0, stream>>>(esrc, edst, deg_out, deg_in);
    gemm_kernel<<<(N_NODESC + 127) / 128, 256, 0, stream>>>(
        feat, fc1w, fc1b, fltw, fltb, deg_out, h1, xs);
    scanA_kernel<<<NBLK_SCAN, 1024, 0, stream>>>(deg_in, cursor /*part scratch*/, blk_sums);
    scanB_kernel<<<1, 64, 0, stream>>>(blk_sums, blk_off);
    scanC_kernel<<<(N_NODESC + 256) / 256, 256, 0, stream>>>(cursor, blk_off, row_start, cursor);
    fill_kernel<<<1024, 256, 0, stream>>>(esrc, edst, cursor, srcs);
    agg_kernel<<<(N_NODESC + 3) / 4, 256, 0, stream>>>(row_start, srcs, xs, h2);
    att_kernel<<<(N_NODESC + 255) / 256, 256, 0, stream>>>(h1, h2, aw1, ab1, aw2, wsum);
    beta_kernel<<<1, 1, 0, stream>>>(wsum, beta);
    out_kernel<<<(N_NODESC + 15) / 16, 256, 0, stream>>>(h1, h2, beta, fc2w, fc2b, out);
}